// Round 4
// baseline (376.931 us; speedup 1.0000x reference)
//
#include <hip/hip_runtime.h>

#define BB  65536
#define INW 128
#define HH  256
#define MM  32
#define KK  (INW + HH)   // 384
#define NKC 12           // 32-wide K chunks in the main GEMM

typedef __attribute__((ext_vector_type(8))) short bf16x8;
typedef __attribute__((ext_vector_type(4))) float f32x4;

#define SB() __builtin_amdgcn_sched_barrier(0)
// asm-pinned 16B load: forces a distinct live dest VGPR quad and a fixed
// issue position (rounds 0-3: plain loads + fences always got re-serialized).
#define GL4(dst, ptr) asm volatile("global_load_dwordx4 %0, %1, off" : "=v"(dst) : "v"(ptr) : "memory")
// full drain + scheduling fence (rule #18: SB required after an asm waitcnt)
#define WAITV0() do { asm volatile("s_waitcnt vmcnt(0)" ::: "memory"); __builtin_amdgcn_sched_barrier(0); } while (0)

__device__ __forceinline__ unsigned short f32_to_bf16(float f) {
    union { float f; unsigned u; } v; v.f = f;
    return (unsigned short)((v.u + 0x7fffu + ((v.u >> 16) & 1u)) >> 16);
}

__device__ __forceinline__ bf16x8 cvt8(f32x4 a, f32x4 b) {
    bf16x8 r;
    r[0] = (short)f32_to_bf16(a[0]); r[1] = (short)f32_to_bf16(a[1]);
    r[2] = (short)f32_to_bf16(a[2]); r[3] = (short)f32_to_bf16(a[3]);
    r[4] = (short)f32_to_bf16(b[0]); r[5] = (short)f32_to_bf16(b[1]);
    r[6] = (short)f32_to_bf16(b[2]); r[7] = (short)f32_to_bf16(b[3]);
    return r;
}

__device__ __forceinline__ float rcp_f(float x) { return __builtin_amdgcn_rcpf(x); }
__device__ __forceinline__ float sigmoid_f(float x) { return rcp_f(1.0f + __expf(-x)); }
__device__ __forceinline__ float tanh_f(float x) { return 1.0f - 2.0f * rcp_f(__expf(2.0f * x) + 1.0f); }

// ---- weight fp32 -> bf16, packed fragment-major (unchanged layout) ----
// Wi_p: [half][kc][t][512], Wm_p: [half][t][512]; fragment = 512 bf16 = 1KB.
__global__ void pack_weights(const float* __restrict__ Wi, const float* __restrict__ Wm,
                             unsigned short* __restrict__ Wi_p, unsigned short* __restrict__ Wm_p) {
    int id = blockIdx.x * 256 + threadIdx.x;
    if (id < 2 * NKC * 8 * 512) {
        int blk = id >> 9;
        int e   = id & 511;
        int lane = e >> 3, j = e & 7;
        int lrow = lane & 15, quad = lane >> 4;
        int h  = blk / (NKC * 8);
        int b  = blk % (NKC * 8);
        int kc = b >> 3;
        int t  = b & 7;
        int n  = h * 128 + t * 16 + lrow;
        int k  = kc * 32 + quad * 8 + j;
        Wi_p[id] = f32_to_bf16(Wi[(size_t)n * KK + k]);
    }
    if (id < 2 * 8 * 512) {
        int blk = id >> 9;
        int e   = id & 511;
        int lane = e >> 3, j = e & 7;
        int lrow = lane & 15, quad = lane >> 4;
        int h = blk >> 3;
        int t = blk & 7;
        int n = h * 128 + t * 16 + lrow;
        Wm_p[id] = f32_to_bf16(Wm[(size_t)n * MM + quad * 8 + j]);
    }
}

// ---- epilogue math for one tile t: 4 outputs per lane ----
__device__ __forceinline__ void epilogue4(f32x4 g4, f32x4 am, f32x4 ct4, f32x4 bi4, f32x4 bm4,
                                          float* __restrict__ p, size_t outH) {
    f32x4 h4, c4;
#pragma unroll
    for (int r = 0; r < 4; ++r) {
        float g    = g4[r] + bi4[r];
        float mp   = am[r] + bm4[r];
        float gate = sigmoid_f(g);
        float tg   = tanh_f(g);
        float c    = ct4[r] * gate + tg * gate;
        float cr   = tanh_f(c);
        float mg   = sigmoid_f(mp);
        float cf   = c - cr + cr * mg;
        float h    = tanh_f(cf) * gate;
        h4[r] = h; c4[r] = c;
    }
    __builtin_nontemporal_store(h4, (f32x4*)p);
    __builtin_nontemporal_store(h4, (f32x4*)(p + outH));
    __builtin_nontemporal_store(c4, (f32x4*)(p + 2 * outH));
}

// ---- fused RLSTM: LDS weights + asm-pinned deep load bursts ----
// Block = 256 thr (4 waves), one 64-wide n-quarter, 128 batch rows.
// XCD swizzle colocates the 4 quarters of a row-block on one XCD's L2,
// so activation HBM traffic is 1x (round-3 regression: 4x).
// Loads: 30 asm global_load_dwordx4 per tile, issued a full phase early
// (tile 0 under weight staging; tile 1 under tile-0 epilogue) -> only
// drains are the staging __syncthreads and one vmcnt(0) between tiles.
__global__ __launch_bounds__(256, 2) void rlstm_main(
    const float* __restrict__ input, const float* __restrict__ media,
    const float* __restrict__ h_t,   const float* __restrict__ c_t,
    const unsigned short* __restrict__ Wi_p, const float* __restrict__ bi,
    const unsigned short* __restrict__ Wm_p, const float* __restrict__ bm,
    float* __restrict__ out)
{
    __shared__ unsigned short wiq[NKC * 4 * 512];   // 48 KB: [kc][t'][512]
    __shared__ unsigned short wmq[4 * 512];         // 4 KB:  [t'][512]
    __shared__ float lbi[64], lbm[64];

    const int tid  = threadIdx.x;
    const int wave = tid >> 6;
    const int lane = tid & 63;
    const int lrow = lane & 15;
    const int quad = lane >> 4;

    // hw xcd = blockIdx % 8 (round-robin); give the 4 quarter-blocks of a
    // row-block the same residue -> same XCD -> shared L2 act lines.
    const int bid = blockIdx.x;
    const int vid = (bid & 7) * 256 + (bid >> 3);   // bijective: 2048 = 8 * 256
    const int q      = vid & 3;                     // n-quarter
    const int rowblk = vid >> 2;
    const int half   = q >> 1;
    const int thalf  = q & 1;
    const int n0q    = q * 64;

    const int arow0 = rowblk * 128 + wave * 16 + lrow;
    const int arow1 = arow0 + 64;
    const size_t rb0 = (size_t)arow0 * HH + n0q;
    const size_t rb1 = (size_t)arow1 * HH + n0q;

    // ---- tile-0 batch: 30 asm loads, in flight under the weight staging ----
    f32x4 a[24], ct0[4], md00, md01;
#pragma unroll
    for (int kc = 0; kc < NKC; ++kc) {
        const float* s = (kc < 4) ? input + (size_t)arow0 * INW + kc * 32 + quad * 8
                                  : h_t   + (size_t)arow0 * HH  + (kc - 4) * 32 + quad * 8;
        GL4(a[2 * kc], s);
        GL4(a[2 * kc + 1], s + 4);
    }
#pragma unroll
    for (int t = 0; t < 4; ++t) GL4(ct0[t], c_t + rb0 + t * 16 + quad * 4);
    GL4(md00, media + (size_t)arow0 * MM + quad * 8);
    GL4(md01, media + (size_t)arow0 * MM + quad * 8 + 4);

    // ---- stage this block's weight quarter into LDS (once) ----
#pragma unroll
    for (int r = 0; r < 12; ++r) {
        int le  = (r * 256 + tid) * 8;
        int kc  = le >> 11;
        int rem = le & 2047;
        bf16x8 v = *(const bf16x8*)(Wi_p + (size_t)(half * NKC + kc) * 4096 + thalf * 2048 + rem);
        *(bf16x8*)(wiq + le) = v;
    }
    {
        int le = tid * 8;
        bf16x8 v = *(const bf16x8*)(Wm_p + (size_t)half * 4096 + thalf * 2048 + le);
        *(bf16x8*)(wmq + le) = v;
    }
    if (tid < 64)        lbi[tid]      = bi[n0q + tid];
    else if (tid < 128)  lbm[tid - 64] = bm[n0q + (tid - 64)];
    WAITV0();
    __syncthreads();   // drains vmcnt+lgkmcnt: every tile-0 operand now in regs

    const size_t outH = (size_t)BB * HH;

    // ---- tile 0 GEMM: zero waits (operands resident) ----
    f32x4 acc[4];
#pragma unroll
    for (int t = 0; t < 4; ++t) acc[t] = (f32x4){0.f, 0.f, 0.f, 0.f};
#pragma unroll
    for (int kc = 0; kc < NKC; ++kc) {
        bf16x8 xa = cvt8(a[2 * kc], a[2 * kc + 1]);
#pragma unroll
        for (int t = 0; t < 4; ++t) {
            bf16x8 wf = *(const bf16x8*)(wiq + kc * 2048 + t * 512 + lane * 8);
            acc[t] = __builtin_amdgcn_mfma_f32_16x16x32_bf16(wf, xa, acc[t], 0, 0, 0);
        }
    }
    SB();

    // ---- tile-1 batch issued now; tile-0 epilogue (~800cy) covers it ----
    f32x4 ct1[4], md10, md11;
#pragma unroll
    for (int kc = 0; kc < NKC; ++kc) {
        const float* s = (kc < 4) ? input + (size_t)arow1 * INW + kc * 32 + quad * 8
                                  : h_t   + (size_t)arow1 * HH  + (kc - 4) * 32 + quad * 8;
        GL4(a[2 * kc], s);            // old a[] values all dead (read above)
        GL4(a[2 * kc + 1], s + 4);
    }
#pragma unroll
    for (int t = 0; t < 4; ++t) GL4(ct1[t], c_t + rb1 + t * 16 + quad * 4);
    GL4(md10, media + (size_t)arow1 * MM + quad * 8);
    GL4(md11, media + (size_t)arow1 * MM + quad * 8 + 4);
    SB();

    // ---- epilogue tile 0 ----
    {
        bf16x8 mf = cvt8(md00, md01);
#pragma unroll
        for (int t = 0; t < 4; ++t) {
            bf16x8 wmf = *(const bf16x8*)(wmq + t * 512 + lane * 8);
            f32x4 am = __builtin_amdgcn_mfma_f32_16x16x32_bf16(
                wmf, mf, (f32x4){0.f, 0.f, 0.f, 0.f}, 0, 0, 0);
            const int nb = t * 16 + quad * 4;
            f32x4 bi4 = *(const f32x4*)(lbi + nb);
            f32x4 bm4 = *(const f32x4*)(lbm + nb);
            epilogue4(acc[t], am, ct0[t], bi4, bm4, out + rb0 + nb, outH);
        }
    }

    // ---- tile 1: one robust drain, then waitless compute ----
    WAITV0();
#pragma unroll
    for (int t = 0; t < 4; ++t) acc[t] = (f32x4){0.f, 0.f, 0.f, 0.f};
#pragma unroll
    for (int kc = 0; kc < NKC; ++kc) {
        bf16x8 xa = cvt8(a[2 * kc], a[2 * kc + 1]);
#pragma unroll
        for (int t = 0; t < 4; ++t) {
            bf16x8 wf = *(const bf16x8*)(wiq + kc * 2048 + t * 512 + lane * 8);
            acc[t] = __builtin_amdgcn_mfma_f32_16x16x32_bf16(wf, xa, acc[t], 0, 0, 0);
        }
    }
    {
        bf16x8 mf = cvt8(md10, md11);
#pragma unroll
        for (int t = 0; t < 4; ++t) {
            bf16x8 wmf = *(const bf16x8*)(wmq + t * 512 + lane * 8);
            f32x4 am = __builtin_amdgcn_mfma_f32_16x16x32_bf16(
                wmf, mf, (f32x4){0.f, 0.f, 0.f, 0.f}, 0, 0, 0);
            const int nb = t * 16 + quad * 4;
            f32x4 bi4 = *(const f32x4*)(lbi + nb);
            f32x4 bm4 = *(const f32x4*)(lbm + nb);
            epilogue4(acc[t], am, ct1[t], bi4, bm4, out + rb1 + nb, outH);
        }
    }
}

extern "C" void kernel_launch(void* const* d_in, const int* in_sizes, int n_in,
                              void* d_out, int out_size, void* d_ws, size_t ws_size,
                              hipStream_t stream) {
    const float* input = (const float*)d_in[0];
    const float* media = (const float*)d_in[1];
    const float* h_t   = (const float*)d_in[2];
    const float* c_t   = (const float*)d_in[3];
    const float* Wi    = (const float*)d_in[4];
    const float* bi    = (const float*)d_in[5];
    const float* Wm    = (const float*)d_in[6];
    const float* bm    = (const float*)d_in[7];
    float* out = (float*)d_out;

    unsigned short* Wi_p = (unsigned short*)d_ws;
    unsigned short* Wm_p = Wi_p + 2 * NKC * 8 * 512;

    hipLaunchKernelGGL(pack_weights, dim3((2 * NKC * 8 * 512 + 255) / 256), dim3(256), 0, stream,
                       Wi, Wm, Wi_p, Wm_p);
    // grid: 512 row-blocks x 4 n-quarters (swizzled in-kernel)
    hipLaunchKernelGGL(rlstm_main, dim3(512 * 4), dim3(256), 0, stream,
                       input, media, h_t, c_t, Wi_p, bi, Wm_p, bm, out);
}